// Round 10
// baseline (75.355 us; speedup 1.0000x reference)
//
#include <hip/hip_runtime.h>

typedef _Float16 f16;
typedef f16   f16x4 __attribute__((ext_vector_type(4)));
typedef f16   f16x8 __attribute__((ext_vector_type(8)));
typedef float f32x4 __attribute__((ext_vector_type(4)));

#define E 512
#define BM 128
#define BN 128
#define BK 32
#define NT 16            /* K-steps */
#define N_TILES 4

// counted waitcnt + barrier (T4): N = per-wave loads still allowed in flight
#define WAIT_BAR(N) asm volatile("s_waitcnt vmcnt(" #N ")\n\ts_barrier" ::: "memory")
#define BAR()       asm volatile("s_barrier" ::: "memory")

// direct global->LDS async copy, 16B/lane; dst = wave-uniform base + lane*16
__device__ __forceinline__ void load_lds16(const void* g, void* l) {
    __builtin_amdgcn_global_load_lds(
        (const __attribute__((address_space(1))) unsigned int*)g,
        (__attribute__((address_space(3))) unsigned int*)l,
        16, 0, 0);
}

// ---------------------------------------------------------------------------
// Weight convert: Wq, Wo (fp32 [512][512] row-major) -> f16 row-major copies
// ---------------------------------------------------------------------------
__global__ void convert_w_kernel(const float* __restrict__ wq,
                                 const float* __restrict__ wo,
                                 f16* __restrict__ wq_h,
                                 f16* __restrict__ wo_h) {
    int i = blockIdx.x * blockDim.x + threadIdx.x;
    const int n4 = (512 * 512) / 4;
    const float4* src; f16* dst;
    if (i < n4) { src = (const float4*)wq; dst = wq_h; }
    else        { src = (const float4*)wo; dst = wo_h; i -= n4; }
    float4 v = src[i];
    f16* p = dst + (size_t)i * 4;
    p[0] = (f16)v.x; p[1] = (f16)v.y; p[2] = (f16)v.z; p[3] = (f16)v.w;
}

// ---------------------------------------------------------------------------
// GEMM1: meas = cumprod8(cos(x @ Wq^T)), x fp32, output f16.
// A staged as fp32 via global_load_lds with SOURCE-granule XOR swizzle
// (slot (row,p) holds source granule p^(row&7): fragment b128 reads spread
// over all 32 banks instead of 16). B (f16 weights) linear (bank-uniform).
// Counted-vmcnt schedule: per step t --
//   WAIT_BAR(6)  [stage(t) landed; stage(t+1)'s 6 loads stay in flight]
//   ds_read buf[t&1] (+cvt) ; 16 MFMA (swapped operands)
//   BAR ; issue stage(t+2) -> buf[t&1]          (depth-2 across barriers)
// 256 thr = 4 waves (2x2), wave tile 64x64, mfma_f32_16x16x32_f16.
// LDS 48KB -> 3 blocks/CU.
// ---------------------------------------------------------------------------
__global__ __launch_bounds__(256, 3)
void gemm_q_kernel(const float* __restrict__ X,
                   const f16* __restrict__ B,
                   f16* __restrict__ C) {
    __shared__ __align__(16) char As[2][BM * BK * 4];   // fp32 tile, 16KB/buf
    __shared__ __align__(16) char Bs[2][BN * BK * 2];   // f16 tile,   8KB/buf

    const int tid  = threadIdx.x;
    const int lane = tid & 63;
    const int wave = tid >> 6;
    const int wm = (wave >> 1) * 64;
    const int wn = (wave & 1) * 64;
    const int fr = lane & 15;
    const int kq = lane >> 4;

    const int bid = blockIdx.x;
    const int chunk = gridDim.x >> 3;
    const int swz = (bid & 7) * chunk + (bid >> 3);
    const int m0 = (swz >> 2) * BM;
    const int n0 = (swz & 3) * BN;

    // stage one K-tile (6 loads/wave: 4 A + 2 B)
    auto stage = [&](int buf, int kt) {
        const int k0 = kt * BK;
#pragma unroll
        for (int c = 0; c < 4; ++c) {                 // A: 16 x 1KB chunks
            const int ch = wave * 4 + c;
            const int s = ch * 64 + lane;             // LDS granule slot
            const int row = s >> 3;
            const int g = (s & 7) ^ (row & 7);        // source granule (XOR swz)
            const float* src = X + (size_t)(m0 + row) * E + k0 + g * 4;
            load_lds16(src, As[buf] + ch * 1024);
        }
#pragma unroll
        for (int c = 0; c < 2; ++c) {                 // B: 8 x 1KB chunks, linear
            const int ch = wave * 2 + c;
            const int G = ch * 64 + lane;             // row=G>>2, colg=(G&3)*8
            const f16* src = B + (size_t)(n0 + (G >> 2)) * E + k0 + (G & 3) * 8;
            load_lds16(src, Bs[buf] + ch * 1024);
        }
    };

    f32x4 acc[4][4] = {};

    stage(0, 0);
    stage(1, 1);

#pragma unroll
    for (int t = 0; t < NT; ++t) {
        const int cur = t & 1;
        if (t + 1 < NT) { WAIT_BAR(6); } else { WAIT_BAR(0); }

        f16x8 afr[4], bfr[4];
#pragma unroll
        for (int i = 0; i < 4; ++i) {                 // A: 2 swizzled f32x4 + cvt
            const int r = wm + i * 16 + fr;
            const float* base = (const float*)As[cur] + r * 32;
            const int p0 = (kq * 2) ^ (r & 7);
            const int p1 = (kq * 2 + 1) ^ (r & 7);
            f32x4 a0 = *(const f32x4*)(base + p0 * 4);
            f32x4 a1 = *(const f32x4*)(base + p1 * 4);
#pragma unroll
            for (int q = 0; q < 4; ++q) { afr[i][q] = (f16)a0[q]; afr[i][4 + q] = (f16)a1[q]; }
        }
#pragma unroll
        for (int j = 0; j < 4; ++j)
            bfr[j] = *(const f16x8*)&((const f16*)Bs[cur])[(wn + j * 16 + fr) * BK + kq * 8];

        // swapped operands: m = lane&15, n = (lane>>4)*4 + reg
#pragma unroll
        for (int i = 0; i < 4; ++i)
#pragma unroll
            for (int j = 0; j < 4; ++j)
                acc[i][j] = __builtin_amdgcn_mfma_f32_16x16x32_f16(
                    bfr[j], afr[i], acc[i][j], 0, 0, 0);

        BAR();
        if (t + 2 < NT) stage(cur, t + 2);            // refill just-read buffer
    }

    // epilogue: cumprod(cos) over 8-wide n-groups; partner = lane^16
#pragma unroll
    for (int i = 0; i < 4; ++i) {
        const int row = m0 + wm + i * 16 + fr;
#pragma unroll
        for (int j = 0; j < 4; ++j) {
            float c0 = __cosf(acc[i][j][0]);
            float c1 = c0 * __cosf(acc[i][j][1]);
            float c2 = c1 * __cosf(acc[i][j][2]);
            float c3 = c2 * __cosf(acc[i][j][3]);
            float ptot = __shfl_xor(c3, 16, 64);
            float f = (kq & 1) ? ptot : 1.0f;         // odd quad = upper half
            f16x4 v = { (f16)(c0 * f), (f16)(c1 * f), (f16)(c2 * f), (f16)(c3 * f) };
            const int col = n0 + wn + j * 16 + kq * 4;
            *(f16x4*)&C[(size_t)row * E + col] = v;
        }
    }
}

// ---------------------------------------------------------------------------
// GEMM2: out = meas @ Wo^T, both f16, fp32 output. Same counted-vmcnt
// schedule, L = 4 (2 A + 2 B gload_lds per wave). Linear f16 LDS tiles
// (full-wave b128 is bank-uniform). LDS 32KB -> 4-5 blocks/CU.
// ---------------------------------------------------------------------------
__global__ __launch_bounds__(256, 4)
void gemm_o_kernel(const f16* __restrict__ A,
                   const f16* __restrict__ B,
                   float* __restrict__ Out) {
    __shared__ __align__(16) char As[2][BM * BK * 2];   // 8KB/buf
    __shared__ __align__(16) char Bs[2][BN * BK * 2];   // 8KB/buf

    const int tid  = threadIdx.x;
    const int lane = tid & 63;
    const int wave = tid >> 6;
    const int wm = (wave >> 1) * 64;
    const int wn = (wave & 1) * 64;
    const int fr = lane & 15;
    const int kq = lane >> 4;

    const int bid = blockIdx.x;
    const int chunk = gridDim.x >> 3;
    const int swz = (bid & 7) * chunk + (bid >> 3);
    const int m0 = (swz >> 2) * BM;
    const int n0 = (swz & 3) * BN;

    auto stage = [&](int buf, int kt) {
        const int k0 = kt * BK;
#pragma unroll
        for (int c = 0; c < 2; ++c) {
            const int ch = wave * 2 + c;
            const int G = ch * 64 + lane;
            const f16* srcA = A + (size_t)(m0 + (G >> 2)) * E + k0 + (G & 3) * 8;
            load_lds16(srcA, As[buf] + ch * 1024);
        }
#pragma unroll
        for (int c = 0; c < 2; ++c) {
            const int ch = wave * 2 + c;
            const int G = ch * 64 + lane;
            const f16* srcB = B + (size_t)(n0 + (G >> 2)) * E + k0 + (G & 3) * 8;
            load_lds16(srcB, Bs[buf] + ch * 1024);
        }
    };

    f32x4 acc[4][4] = {};

    stage(0, 0);
    stage(1, 1);

#pragma unroll
    for (int t = 0; t < NT; ++t) {
        const int cur = t & 1;
        if (t + 1 < NT) { WAIT_BAR(4); } else { WAIT_BAR(0); }

        f16x8 afr[4], bfr[4];
#pragma unroll
        for (int i = 0; i < 4; ++i)
            afr[i] = *(const f16x8*)&((const f16*)As[cur])[(wm + i * 16 + fr) * BK + kq * 8];
#pragma unroll
        for (int j = 0; j < 4; ++j)
            bfr[j] = *(const f16x8*)&((const f16*)Bs[cur])[(wn + j * 16 + fr) * BK + kq * 8];

#pragma unroll
        for (int i = 0; i < 4; ++i)
#pragma unroll
            for (int j = 0; j < 4; ++j)
                acc[i][j] = __builtin_amdgcn_mfma_f32_16x16x32_f16(
                    bfr[j], afr[i], acc[i][j], 0, 0, 0);

        BAR();
        if (t + 2 < NT) stage(cur, t + 2);
    }

    // store: m = lane&15, n-quad = (lane>>4)*4 -> f32x4 contiguous
#pragma unroll
    for (int i = 0; i < 4; ++i) {
        const int row = m0 + wm + i * 16 + fr;
#pragma unroll
        for (int j = 0; j < 4; ++j) {
            const int col = n0 + wn + j * 16 + kq * 4;
            *(f32x4*)&Out[(size_t)row * E + col] = acc[i][j];
        }
    }
}

// ---------------------------------------------------------------------------
extern "C" void kernel_launch(void* const* d_in, const int* in_sizes, int n_in,
                              void* d_out, int out_size, void* d_ws, size_t ws_size,
                              hipStream_t stream) {
    const float* x  = (const float*)d_in[0];
    const float* Wq = (const float*)d_in[1];
    // d_in[2]=Wk, d_in[3]=Wv: dead compute in the reference
    const float* Wo = (const float*)d_in[4];

    const int M = in_sizes[0] / E;   // 32768

    f16* wq_h = (f16*)d_ws;                  // 512 KB
    f16* wo_h = wq_h + 512 * 512;            // 512 KB
    f16* meas = wo_h + 512 * 512;            // 32 MB

    convert_w_kernel<<<512, 256, 0, stream>>>(Wq, Wo, wq_h, wo_h);

    const int nblk = (M / BM) * N_TILES;     // 1024
    gemm_q_kernel<<<nblk, 256, 0, stream>>>(x, wq_h, meas);
    gemm_o_kernel<<<nblk, 256, 0, stream>>>(meas, wo_h, (float*)d_out);
}